// Round 2
// baseline (5927.192 us; speedup 1.0000x reference)
//
#include <hip/hip_runtime.h>
#include <stdint.h>

#define HEADS 16
#define B_SZ  4
#define S_SZ  4096
#define E_SZ  2048
#define M_SZ  (B_SZ * S_SZ)      // 16384 rows
#define NQKV  (3 * E_SZ)         // 6144

typedef short bf16x8 __attribute__((ext_vector_type(8)));
typedef float f32x4  __attribute__((ext_vector_type(4)));

__device__ __forceinline__ float bf2f(uint16_t u) {
  union { uint32_t i; float f; } v; v.i = ((uint32_t)u) << 16; return v.f;
}
__device__ __forceinline__ uint16_t f2bf(float f) {
  union { float f; uint32_t i; } v; v.f = f;
  uint32_t r = v.i + 0x7FFFu + ((v.i >> 16) & 1u);   // RNE
  return (uint16_t)(r >> 16);
}

// XOR bank swizzles (flash LDS): column ^ ((row&7)<<3) — bijective within each
// 8-row stripe, preserves 16B alignment, spreads stride-256B/128B column reads
// across all 32 banks (residual 2-way = free). [verified r1: conflicts 7.3e8->6.7e7]
__device__ __forceinline__ int swz128(int row, int col) {  // col 0..127
  return row * 128 + (col ^ ((row & 7) << 3));
}
__device__ __forceinline__ int swz64(int row, int col) {   // col 0..63
  return row * 64 + (col ^ ((row & 7) << 3));
}

// ------------------------------------------------------------- dtype probe
// flag=1 -> inputs are f32 read as uint16 halves (garbage at even indices)
__global__ __launch_bounds__(64) void probe_kernel(
    const uint16_t* __restrict__ x, uint32_t* __restrict__ flag) {
  int tid = threadIdx.x;
  int cnt = 0;
  for (int i = tid; i < 4096; i += 64) {
    uint16_t u = x[2 * i];
    int e = (u >> 7) & 0xFF;
    cnt += (e >= 134) ? 1 : 0;    // |v| >= 128 or NaN/Inf: impossible for N(0,1) bf16
  }
#pragma unroll
  for (int off = 1; off < 64; off <<= 1) cnt += __shfl_xor(cnt, off, 64);
  if (tid == 0) flag[0] = (cnt > 256) ? 1u : 0u;
}

// ---------------------------------------------------------------- LayerNorm
__global__ __launch_bounds__(256) void ln_kernel(
    const uint16_t* __restrict__ x, const uint16_t* __restrict__ w,
    const uint16_t* __restrict__ b, uint16_t* __restrict__ xn,
    const uint32_t* __restrict__ flag) {
  const bool f32m = flag[0] != 0;
  int row = blockIdx.x;
  int tid = threadIdx.x;
  float v[8], wv[8], bv[8];
  if (f32m) {
    const float* xr = (const float*)x + (size_t)row * E_SZ;
    float4 a0 = ((const float4*)xr)[tid * 2], a1 = ((const float4*)xr)[tid * 2 + 1];
    v[0]=a0.x; v[1]=a0.y; v[2]=a0.z; v[3]=a0.w; v[4]=a1.x; v[5]=a1.y; v[6]=a1.z; v[7]=a1.w;
    const float* wf = (const float*)w; const float* bf = (const float*)b;
    float4 w0 = ((const float4*)wf)[tid * 2], w1 = ((const float4*)wf)[tid * 2 + 1];
    float4 b0 = ((const float4*)bf)[tid * 2], b1 = ((const float4*)bf)[tid * 2 + 1];
    wv[0]=w0.x; wv[1]=w0.y; wv[2]=w0.z; wv[3]=w0.w; wv[4]=w1.x; wv[5]=w1.y; wv[6]=w1.z; wv[7]=w1.w;
    bv[0]=b0.x; bv[1]=b0.y; bv[2]=b0.z; bv[3]=b0.w; bv[4]=b1.x; bv[5]=b1.y; bv[6]=b1.z; bv[7]=b1.w;
  } else {
    const uint16_t* xr = x + (size_t)row * E_SZ;
    uint4 pack = ((const uint4*)xr)[tid];
    uint4 wp = ((const uint4*)w)[tid];
    uint4 bp = ((const uint4*)b)[tid];
    const uint16_t* pu = (const uint16_t*)&pack;
    const uint16_t* pw = (const uint16_t*)&wp;
    const uint16_t* pb = (const uint16_t*)&bp;
#pragma unroll
    for (int i = 0; i < 8; i++) { v[i] = bf2f(pu[i]); wv[i] = bf2f(pw[i]); bv[i] = bf2f(pb[i]); }
  }
  float sum = 0.f, ss = 0.f;
#pragma unroll
  for (int i = 0; i < 8; i++) {
    v[i] = (v[i] == v[i]) ? v[i] : 0.f;        // scrub NaN (input-facing, keep)
    sum += v[i]; ss += v[i] * v[i];
  }
#pragma unroll
  for (int off = 1; off < 64; off <<= 1) {
    sum += __shfl_xor(sum, off, 64);
    ss  += __shfl_xor(ss,  off, 64);
  }
  __shared__ float s_sum[4], s_ss[4];
  int wave = tid >> 6, lane = tid & 63;
  if (lane == 0) { s_sum[wave] = sum; s_ss[wave] = ss; }
  __syncthreads();
  sum = s_sum[0] + s_sum[1] + s_sum[2] + s_sum[3];
  ss  = s_ss[0]  + s_ss[1]  + s_ss[2]  + s_ss[3];
  float mean = sum * (1.0f / E_SZ);
  float var  = fmaxf(ss * (1.0f / E_SZ) - mean * mean, 0.0f);
  float rstd = rsqrtf(var + 1e-5f);
  uint16_t o[8];
#pragma unroll
  for (int i = 0; i < 8; i++)
    o[i] = f2bf((v[i] - mean) * rstd * wv[i] + bv[i]);
  ((uint4*)(xn + (size_t)row * E_SZ))[tid] = *(const uint4*)o;
}

// ------------------------------------------------- 128x128 MFMA GEMM (B^T)
// C[m,n] = sum_k A[m,k]*Bm[n,k] + bias[n];  A is internal bf16 always.
// LDS rows padded to 40 elements (80B): row bank-base steps by 20 -> both the
// b128 reads AND writes go from ~8-way conflicts to ~2-way (free).
// Reg-prefetch pipeline: next K-tile's global loads issued right after the
// barrier, consumed at next loop top (T3-minimal 2-phase).
// EPI==0: scatter qkv -> q[B,H,S,hd], k[B,H,S,hd], vT[B,H,hd,S] (internal bf16)
// EPI==1: row-major store to Cout[M][Ndim] (dtype per flag)
#define GLD 40   // padded leading dim (elements)
template <int EPI>
__global__ __launch_bounds__(256) void gemm_bt(
    const uint16_t* __restrict__ A, const uint16_t* __restrict__ Bm,
    const uint16_t* __restrict__ bias, uint16_t* __restrict__ Cq,
    uint16_t* __restrict__ Ck, uint16_t* __restrict__ Cv,
    uint16_t* __restrict__ Cout, int Ndim, const uint32_t* __restrict__ flag) {
  const bool f32m = flag[0] != 0;
  __shared__ __align__(16) uint16_t As[128 * GLD];
  __shared__ __align__(16) uint16_t Bs[128 * GLD];
  int tid = threadIdx.x;
  int wave = tid >> 6, lane = tid & 63;
  int quad = lane >> 4, l16 = lane & 15;
  int m0 = blockIdx.y * 128, n0 = blockIdx.x * 128;
  int wm = (wave >> 1) * 64, wn = (wave & 1) * 64;

  f32x4 acc[4][4] = {};

  const int rw_ = (tid * 8) >> 5;       // this thread's tile row (same for r via +64)
  const int cl_ = (tid * 8) & 31;       // this thread's tile col

  uint4 pa[2], pbb[2];
  float4 pbf[4];

  auto LOADK = [&](int k0) {
#pragma unroll
    for (int r = 0; r < 2; r++) {
      int rw = rw_ + r * 64;
      pa[r] = *(const uint4*)(A + (size_t)(m0 + rw) * E_SZ + k0 + cl_);
      if (f32m) {
        const float* Bf = (const float*)Bm + (size_t)(n0 + rw) * E_SZ + k0 + cl_;
        pbf[2 * r]     = *(const float4*)(Bf);
        pbf[2 * r + 1] = *(const float4*)(Bf + 4);
      } else {
        pbb[r] = *(const uint4*)(Bm + (size_t)(n0 + rw) * E_SZ + k0 + cl_);
      }
    }
  };

  LOADK(0);
  for (int kt = 0; kt < E_SZ / 32; kt++) {
    // stage regs -> LDS
#pragma unroll
    for (int r = 0; r < 2; r++) {
      int rw = rw_ + r * 64;
      *(uint4*)&As[rw * GLD + cl_] = pa[r];
      uint16_t pbv[8];
      if (f32m) {
        float4 x0 = pbf[2 * r], x1 = pbf[2 * r + 1];
        pbv[0]=f2bf(x0.x); pbv[1]=f2bf(x0.y); pbv[2]=f2bf(x0.z); pbv[3]=f2bf(x0.w);
        pbv[4]=f2bf(x1.x); pbv[5]=f2bf(x1.y); pbv[6]=f2bf(x1.z); pbv[7]=f2bf(x1.w);
      } else {
        *(uint4*)pbv = pbb[r];
      }
      *(uint4*)&Bs[rw * GLD + cl_] = *(const uint4*)pbv;
    }
    __syncthreads();
    if (kt + 1 < E_SZ / 32) LOADK((kt + 1) * 32);   // in flight across compute
    bf16x8 a[4], bb[4];
#pragma unroll
    for (int i = 0; i < 4; i++)
      a[i] = *(const bf16x8*)&As[(wm + i * 16 + l16) * GLD + quad * 8];
#pragma unroll
    for (int j = 0; j < 4; j++)
      bb[j] = *(const bf16x8*)&Bs[(wn + j * 16 + l16) * GLD + quad * 8];
#pragma unroll
    for (int i = 0; i < 4; i++)
#pragma unroll
      for (int j = 0; j < 4; j++)
        acc[i][j] = __builtin_amdgcn_mfma_f32_16x16x32_bf16(a[i], bb[j], acc[i][j], 0, 0, 0);
    __syncthreads();
  }

  float bias_v[4];
#pragma unroll
  for (int j = 0; j < 4; j++) {
    int n = n0 + wn + j * 16 + l16;
    bias_v[j] = f32m ? ((const float*)bias)[n] : bf2f(bias[n]);
    bias_v[j] = (bias_v[j] == bias_v[j]) ? bias_v[j] : 0.f;
  }

  if (EPI == 0) {
    int which = n0 >> 11;             // 0:q 1:k 2:v  (uniform per block)
    int h = (n0 >> 7) & 15;           // uniform per block
    uint16_t* dst = which == 0 ? Cq : (which == 1 ? Ck : Cv);
#pragma unroll
    for (int i = 0; i < 4; i++)
#pragma unroll
      for (int j = 0; j < 4; j++) {
        int d = wn + j * 16 + l16;
#pragma unroll
        for (int r = 0; r < 4; r++) {
          int gm = m0 + wm + i * 16 + quad * 4 + r;
          int bi = gm >> 12, s = gm & 4095;
          float val = acc[i][j][r] + bias_v[j];
          size_t idx;
          if (which == 2) idx = ((size_t)(bi * HEADS + h) * 128 + d) * S_SZ + s;
          else            idx = ((size_t)(bi * HEADS + h) * S_SZ + s) * 128 + d;
          dst[idx] = f2bf(val);
        }
      }
  } else {
#pragma unroll
    for (int i = 0; i < 4; i++)
#pragma unroll
      for (int j = 0; j < 4; j++)
#pragma unroll
        for (int r = 0; r < 4; r++) {
          int gm = m0 + wm + i * 16 + quad * 4 + r;
          int gn = n0 + wn + j * 16 + l16;
          float val = acc[i][j][r] + bias_v[j];
          if (f32m) ((float*)Cout)[(size_t)gm * Ndim + gn] = val;
          else      Cout[(size_t)gm * Ndim + gn] = f2bf(val);
        }
  }
}

// ------------------------------------------------------------------- RoPE
__global__ __launch_bounds__(128) void rope_kernel(
    uint16_t* __restrict__ q, uint16_t* __restrict__ k,
    const uint16_t* __restrict__ position, const uint16_t* __restrict__ freqs,
    const uint32_t* __restrict__ flag) {
  const bool f32m = flag[0] != 0;
  int bs = blockIdx.x;                 // b*4096 + s
  int b = bs >> 12, s = bs & 4095;
  int tid = threadIdx.x;
  int f = tid & 63;
  uint16_t* base = (tid >> 6) ? k : q;
  float fr[3], ps[3];
#pragma unroll
  for (int c = 0; c < 3; c++) {
    fr[c] = f32m ? ((const float*)freqs)[f * 3 + c]    : bf2f(freqs[f * 3 + c]);
    ps[c] = f32m ? ((const float*)position)[s * 3 + c] : bf2f(position[s * 3 + c]);
  }
  float ang = fr[0] * ps[0] + fr[1] * ps[1] + fr[2] * ps[2];
  ang = (ang == ang) ? ang : 0.f;
  float sn = __sinf(ang), c = __cosf(ang);
#pragma unroll
  for (int h = 0; h < HEADS; h++) {
    size_t idx = ((size_t)(b * HEADS + h) * S_SZ + s) * 128 + 2 * f;
    uint32_t pair = *(const uint32_t*)&base[idx];
    float tr = bf2f((uint16_t)(pair & 0xFFFF));
    float ti = bf2f((uint16_t)(pair >> 16));
    float orr = tr * c - ti * sn;
    float oi  = tr * sn + ti * c;
    uint32_t op = (uint32_t)f2bf(orr) | ((uint32_t)f2bf(oi) << 16);
    *(uint32_t*)&base[idx] = op;
  }
}

// --------------------------------------------------------- flash attention
// grid: (S/64 q-tiles, B*H); block: 256 (4 waves x 16 q-rows)
// Changes this round: scrubs removed (K/V/Q are our own finite internal data —
// ~200 dead VALU/thread/tile, more than the tile's 32 MFMAs), and a reg-prefetch
// pipeline: next tile's K/V global loads issue right after the barrier and stay
// in flight under the ~1500-cycle compute phase (T14). Swizzle kept (r1: 11x
// conflict drop). launch_bounds(256,3) pins VGPR so prefetch doesn't cliff.
__global__ __launch_bounds__(256, 3) void flash_kernel(
    const uint16_t* __restrict__ q, const uint16_t* __restrict__ k,
    const uint16_t* __restrict__ vT, uint16_t* __restrict__ attn) {
  __shared__ __align__(16) uint16_t Ks[64 * 128];    // [t][d]  16KB, swizzled
  __shared__ __align__(16) uint16_t VTs[128 * 64];   // [d][t]  16KB, swizzled
  __shared__ __align__(16) uint16_t Ps[4][16 * 64];  // per-wave P  8KB, swizzled
  int tid = threadIdx.x, wave = tid >> 6, lane = tid & 63;
  int quad = lane >> 4, l16 = lane & 15;
  int bh = blockIdx.y;
  int b = bh >> 4, h = bh & 15;
  int q0 = blockIdx.x * 64;
  const uint16_t* qbase = q  + (size_t)bh * S_SZ * 128;
  const uint16_t* kbase = k  + (size_t)bh * S_SZ * 128;
  const uint16_t* vbase = vT + (size_t)bh * 128 * S_SZ;

  // Q fragments in registers (A-operand layout: row=l16, k=quad*8+j)
  bf16x8 aq[4];
  {
    const uint16_t* qrow = qbase + (size_t)(q0 + wave * 16 + l16) * 128;
#pragma unroll
    for (int kk = 0; kk < 4; kk++)
      aq[kk] = *(const bf16x8*)(qrow + kk * 32 + quad * 8);
  }
  float m_run[4], l_run[4];
#pragma unroll
  for (int r = 0; r < 4; r++) { m_run[r] = -1e30f; l_run[r] = 0.f; }
  f32x4 oacc[8] = {};
  const float scale = 0.08838834764831845f;   // 1/sqrt(128)

  // staging geometry (per thread, r in 0..3): e = r*2048 + tid*8
  const int ek_row = (tid * 8) >> 7, ek_col = (tid * 8) & 127;   // +16 rows per r
  const int ev_row = (tid * 8) >> 6, ev_col = (tid * 8) & 63;    // +32 rows per r

  uint4 pk[4], pv[4];
  auto LOADT = [&](int t0) {
#pragma unroll
    for (int r = 0; r < 4; r++) {
      pk[r] = *(const uint4*)(kbase + (size_t)(t0 + ek_row + r * 16) * 128 + ek_col);
      pv[r] = *(const uint4*)(vbase + (size_t)(ev_row + r * 32) * S_SZ + t0 + ev_col);
    }
  };

  LOADT(0);
  for (int t0 = 0; t0 < S_SZ; t0 += 64) {
#pragma unroll
    for (int r = 0; r < 4; r++) {
      *(uint4*)&Ks[swz128(ek_row + r * 16, ek_col)] = pk[r];
      *(uint4*)&VTs[swz64(ev_row + r * 32, ev_col)] = pv[r];
    }
    __syncthreads();
    if (t0 + 64 < S_SZ) LOADT(t0 + 64);    // hide HBM latency under compute

    // S = Q K^T  (16 q-rows x 64 t per wave)
    f32x4 sacc[4] = {};
#pragma unroll
    for (int j = 0; j < 4; j++)
#pragma unroll
      for (int kk = 0; kk < 4; kk++) {
        bf16x8 bk = *(const bf16x8*)&Ks[swz128(j * 16 + l16, kk * 32 + quad * 8)];
        sacc[j] = __builtin_amdgcn_mfma_f32_16x16x32_bf16(aq[kk], bk, sacc[j], 0, 0, 0);
      }

    // online softmax (C rows = quad*4 + r)
    float p[4][4];
#pragma unroll
    for (int r = 0; r < 4; r++) {
      float mx = sacc[0][r];
#pragma unroll
      for (int j = 1; j < 4; j++) mx = fmaxf(mx, sacc[j][r]);
      mx *= scale;
#pragma unroll
      for (int off = 1; off < 16; off <<= 1) mx = fmaxf(mx, __shfl_xor(mx, off, 64));
      float mn = fmaxf(m_run[r], mx);
      float al = __expf(fminf(m_run[r] - mn, 0.f));
      float rs = 0.f;
#pragma unroll
      for (int j = 0; j < 4; j++) {
        float pv_ = __expf(fminf(sacc[j][r] * scale - mn, 0.f));
        p[j][r] = pv_; rs += pv_;
      }
#pragma unroll
      for (int off = 1; off < 16; off <<= 1) rs += __shfl_xor(rs, off, 64);
      l_run[r] = l_run[r] * al + rs;
      m_run[r] = mn;
#pragma unroll
      for (int jd = 0; jd < 8; jd++) oacc[jd][r] *= al;
    }

    // P: C-layout -> LDS -> A-layout. Ps is wave-private: no barrier needed,
    // the compiler's lgkmcnt wait orders the intra-wave ds_write->ds_read.
    uint16_t* ps = &Ps[wave][0];
#pragma unroll
    for (int j = 0; j < 4; j++)
#pragma unroll
      for (int r = 0; r < 4; r++)
        ps[swz64(quad * 4 + r, j * 16 + l16)] = f2bf(p[j][r]);

    bf16x8 ap[2];
#pragma unroll
    for (int kk = 0; kk < 2; kk++)
      ap[kk] = *(const bf16x8*)&ps[swz64(l16, kk * 32 + quad * 8)];
#pragma unroll
    for (int jd = 0; jd < 8; jd++)
#pragma unroll
      for (int kk = 0; kk < 2; kk++) {
        bf16x8 bv = *(const bf16x8*)&VTs[swz64(jd * 16 + l16, kk * 32 + quad * 8)];
        oacc[jd] = __builtin_amdgcn_mfma_f32_16x16x32_bf16(ap[kk], bv, oacc[jd], 0, 0, 0);
      }
    __syncthreads();
  }

  // normalize + write attn[b][s][h*128+d]  (l_run >= 1 by construction)
#pragma unroll
  for (int jd = 0; jd < 8; jd++)
#pragma unroll
    for (int r = 0; r < 4; r++) {
      int srow = q0 + wave * 16 + quad * 4 + r;
      int d = jd * 16 + l16;
      float ov = oacc[jd][r] / fmaxf(l_run[r], 1e-20f);
      attn[((size_t)(b * S_SZ + srow)) * E_SZ + h * 128 + d] = f2bf(ov);
    }
}

// ------------------------------------------------------------------ launch
extern "C" void kernel_launch(void* const* d_in, const int* in_sizes, int n_in,
                              void* d_out, int out_size, void* d_ws, size_t ws_size,
                              hipStream_t stream) {
  const uint16_t* x        = (const uint16_t*)d_in[0];
  const uint16_t* position = (const uint16_t*)d_in[1];
  const uint16_t* ln_w     = (const uint16_t*)d_in[2];
  const uint16_t* ln_b     = (const uint16_t*)d_in[3];
  const uint16_t* qkv_w    = (const uint16_t*)d_in[4];
  const uint16_t* qkv_b    = (const uint16_t*)d_in[5];
  const uint16_t* out_w    = (const uint16_t*)d_in[6];
  const uint16_t* out_b    = (const uint16_t*)d_in[7];
  const uint16_t* freqs    = (const uint16_t*)d_in[8];

  uint8_t* ws = (uint8_t*)d_ws;
  const size_t SLAB = (size_t)M_SZ * E_SZ * 2;   // 67,108,864 B
  uint32_t* flag = (uint32_t*)ws;
  uint16_t* xn   = (uint16_t*)(ws + 1024);       // reused as attn later
  uint16_t* kws  = (uint16_t*)(ws + 1024 + SLAB);
  uint16_t* vTws = (uint16_t*)(ws + 1024 + 2 * SLAB);
  uint16_t* qws  = (uint16_t*)d_out;             // q parks in d_out until final GEMM
  uint16_t* attn = xn;

  probe_kernel<<<1, 64, 0, stream>>>(x, flag);
  ln_kernel<<<M_SZ, 256, 0, stream>>>(x, ln_w, ln_b, xn, flag);
  gemm_bt<0><<<dim3(NQKV / 128, M_SZ / 128), 256, 0, stream>>>(
      xn, qkv_w, qkv_b, qws, kws, vTws, nullptr, 0, flag);
  rope_kernel<<<M_SZ, 128, 0, stream>>>(qws, kws, position, freqs, flag);
  flash_kernel<<<dim3(S_SZ / 64, B_SZ * HEADS), 256, 0, stream>>>(qws, kws, vTws, attn);
  gemm_bt<1><<<dim3(E_SZ / 128, M_SZ / 128), 256, 0, stream>>>(
      attn, out_w, out_b, nullptr, nullptr, nullptr, (uint16_t*)d_out, E_SZ, flag);
}

// Round 3
// 3862.806 us; speedup vs baseline: 1.5344x; 1.5344x over previous
//
#include <hip/hip_runtime.h>
#include <stdint.h>

#define HEADS 16
#define B_SZ  4
#define S_SZ  4096
#define E_SZ  2048
#define M_SZ  (B_SZ * S_SZ)      // 16384 rows
#define NQKV  (3 * E_SZ)         // 6144

typedef short bf16x8 __attribute__((ext_vector_type(8)));
typedef float f32x4  __attribute__((ext_vector_type(4)));

__device__ __forceinline__ float bf2f(uint16_t u) {
  union { uint32_t i; float f; } v; v.i = ((uint32_t)u) << 16; return v.f;
}
__device__ __forceinline__ uint16_t f2bf(float f) {
  union { float f; uint32_t i; } v; v.f = f;
  uint32_t r = v.i + 0x7FFFu + ((v.i >> 16) & 1u);   // RNE
  return (uint16_t)(r >> 16);
}

// XOR bank swizzles (flash LDS): column ^ ((row&7)<<3) — bijective within each
// 8-row stripe, preserves 16B alignment, spreads stride-256B/128B column reads
// across all 32 banks (residual 2-way = free). [verified r1: conflicts 7.3e8->6.7e7]
__device__ __forceinline__ int swz128(int row, int col) {  // col 0..127
  return row * 128 + (col ^ ((row & 7) << 3));
}
__device__ __forceinline__ int swz64(int row, int col) {   // col 0..63
  return row * 64 + (col ^ ((row & 7) << 3));
}

// direct global->LDS 16B copy; LDS dest is wave-uniform base + lane*16 (HW),
// global src is per-lane (pre-swizzled). Compiler never auto-emits this.
__device__ __forceinline__ void gload_lds16(const void* g, void* l) {
  __builtin_amdgcn_global_load_lds(
      (const __attribute__((address_space(1))) uint32_t*)g,
      (__attribute__((address_space(3))) uint32_t*)l, 16, 0, 0);
}

// ------------------------------------------------------------- dtype probe
// flag=1 -> inputs are f32 read as uint16 halves (garbage at even indices)
__global__ __launch_bounds__(64) void probe_kernel(
    const uint16_t* __restrict__ x, uint32_t* __restrict__ flag) {
  int tid = threadIdx.x;
  int cnt = 0;
  for (int i = tid; i < 4096; i += 64) {
    uint16_t u = x[2 * i];
    int e = (u >> 7) & 0xFF;
    cnt += (e >= 134) ? 1 : 0;    // |v| >= 128 or NaN/Inf: impossible for N(0,1) bf16
  }
#pragma unroll
  for (int off = 1; off < 64; off <<= 1) cnt += __shfl_xor(cnt, off, 64);
  if (tid == 0) flag[0] = (cnt > 256) ? 1u : 0u;
}

// ---------------------------------------------------------------- LayerNorm
__global__ __launch_bounds__(256) void ln_kernel(
    const uint16_t* __restrict__ x, const uint16_t* __restrict__ w,
    const uint16_t* __restrict__ b, uint16_t* __restrict__ xn,
    const uint32_t* __restrict__ flag) {
  const bool f32m = flag[0] != 0;
  int row = blockIdx.x;
  int tid = threadIdx.x;
  float v[8], wv[8], bv[8];
  if (f32m) {
    const float* xr = (const float*)x + (size_t)row * E_SZ;
    float4 a0 = ((const float4*)xr)[tid * 2], a1 = ((const float4*)xr)[tid * 2 + 1];
    v[0]=a0.x; v[1]=a0.y; v[2]=a0.z; v[3]=a0.w; v[4]=a1.x; v[5]=a1.y; v[6]=a1.z; v[7]=a1.w;
    const float* wf = (const float*)w; const float* bf = (const float*)b;
    float4 w0 = ((const float4*)wf)[tid * 2], w1 = ((const float4*)wf)[tid * 2 + 1];
    float4 b0 = ((const float4*)bf)[tid * 2], b1 = ((const float4*)bf)[tid * 2 + 1];
    wv[0]=w0.x; wv[1]=w0.y; wv[2]=w0.z; wv[3]=w0.w; wv[4]=w1.x; wv[5]=w1.y; wv[6]=w1.z; wv[7]=w1.w;
    bv[0]=b0.x; bv[1]=b0.y; bv[2]=b0.z; bv[3]=b0.w; bv[4]=b1.x; bv[5]=b1.y; bv[6]=b1.z; bv[7]=b1.w;
  } else {
    const uint16_t* xr = x + (size_t)row * E_SZ;
    uint4 pack = ((const uint4*)xr)[tid];
    uint4 wp = ((const uint4*)w)[tid];
    uint4 bp = ((const uint4*)b)[tid];
    const uint16_t* pu = (const uint16_t*)&pack;
    const uint16_t* pw = (const uint16_t*)&wp;
    const uint16_t* pb = (const uint16_t*)&bp;
#pragma unroll
    for (int i = 0; i < 8; i++) { v[i] = bf2f(pu[i]); wv[i] = bf2f(pw[i]); bv[i] = bf2f(pb[i]); }
  }
  float sum = 0.f, ss = 0.f;
#pragma unroll
  for (int i = 0; i < 8; i++) {
    v[i] = (v[i] == v[i]) ? v[i] : 0.f;        // scrub NaN (input-facing, keep)
    sum += v[i]; ss += v[i] * v[i];
  }
#pragma unroll
  for (int off = 1; off < 64; off <<= 1) {
    sum += __shfl_xor(sum, off, 64);
    ss  += __shfl_xor(ss,  off, 64);
  }
  __shared__ float s_sum[4], s_ss[4];
  int wave = tid >> 6, lane = tid & 63;
  if (lane == 0) { s_sum[wave] = sum; s_ss[wave] = ss; }
  __syncthreads();
  sum = s_sum[0] + s_sum[1] + s_sum[2] + s_sum[3];
  ss  = s_ss[0]  + s_ss[1]  + s_ss[2]  + s_ss[3];
  float mean = sum * (1.0f / E_SZ);
  float var  = fmaxf(ss * (1.0f / E_SZ) - mean * mean, 0.0f);
  float rstd = rsqrtf(var + 1e-5f);
  uint16_t o[8];
#pragma unroll
  for (int i = 0; i < 8; i++)
    o[i] = f2bf((v[i] - mean) * rstd * wv[i] + bv[i]);
  ((uint4*)(xn + (size_t)row * E_SZ))[tid] = *(const uint4*)o;
}

// ------------------------------------------------- 128x128 MFMA GEMM (B^T)
// C[m,n] = sum_k A[m,k]*Bm[n,k] + bias[n];  A is internal bf16 always.
// r1-proven structure (no reg-prefetch, no pad, plain launch_bounds); scrubs
// dropped (A/B are finite: internal bf16 / 0.02-scale weights; r2 verified).
// EPI==0: scatter qkv -> q[B,H,S,hd], k[B,H,S,hd], vT[B,H,hd,S] (internal bf16)
// EPI==1: row-major store to Cout[M][Ndim] (dtype per flag)
template <int EPI>
__global__ __launch_bounds__(256) void gemm_bt(
    const uint16_t* __restrict__ A, const uint16_t* __restrict__ Bm,
    const uint16_t* __restrict__ bias, uint16_t* __restrict__ Cq,
    uint16_t* __restrict__ Ck, uint16_t* __restrict__ Cv,
    uint16_t* __restrict__ Cout, int Ndim, const uint32_t* __restrict__ flag) {
  const bool f32m = flag[0] != 0;
  __shared__ __align__(16) uint16_t As[128 * 32];
  __shared__ __align__(16) uint16_t Bs[128 * 32];
  int tid = threadIdx.x;
  int wave = tid >> 6, lane = tid & 63;
  int quad = lane >> 4, l16 = lane & 15;
  int m0 = blockIdx.y * 128, n0 = blockIdx.x * 128;
  int wm = (wave >> 1) * 64, wn = (wave & 1) * 64;

  f32x4 acc[4][4] = {};

  for (int kt = 0; kt < E_SZ / 32; kt++) {
    int k0 = kt * 32;
#pragma unroll
    for (int r = 0; r < 2; r++) {
      int e = r * 2048 + tid * 8;       // element index in the 128x32 tile
      int rw = e >> 5, cl = e & 31;
      *(uint4*)&As[e] = *(const uint4*)(A + (size_t)(m0 + rw) * E_SZ + k0 + cl);
      if (f32m) {
        const float* Bf = (const float*)Bm + (size_t)(n0 + rw) * E_SZ + k0 + cl;
        float4 x0 = *(const float4*)(Bf);
        float4 x1 = *(const float4*)(Bf + 4);
        uint16_t pbv[8];
        pbv[0]=f2bf(x0.x); pbv[1]=f2bf(x0.y); pbv[2]=f2bf(x0.z); pbv[3]=f2bf(x0.w);
        pbv[4]=f2bf(x1.x); pbv[5]=f2bf(x1.y); pbv[6]=f2bf(x1.z); pbv[7]=f2bf(x1.w);
        *(uint4*)&Bs[e] = *(const uint4*)pbv;
      } else {
        *(uint4*)&Bs[e] = *(const uint4*)(Bm + (size_t)(n0 + rw) * E_SZ + k0 + cl);
      }
    }
    __syncthreads();
    bf16x8 a[4], bb[4];
#pragma unroll
    for (int i = 0; i < 4; i++)
      a[i] = *(const bf16x8*)&As[(wm + i * 16 + l16) * 32 + quad * 8];
#pragma unroll
    for (int j = 0; j < 4; j++)
      bb[j] = *(const bf16x8*)&Bs[(wn + j * 16 + l16) * 32 + quad * 8];
#pragma unroll
    for (int i = 0; i < 4; i++)
#pragma unroll
      for (int j = 0; j < 4; j++)
        acc[i][j] = __builtin_amdgcn_mfma_f32_16x16x32_bf16(a[i], bb[j], acc[i][j], 0, 0, 0);
    __syncthreads();
  }

  float bias_v[4];
#pragma unroll
  for (int j = 0; j < 4; j++) {
    int n = n0 + wn + j * 16 + l16;
    bias_v[j] = f32m ? ((const float*)bias)[n] : bf2f(bias[n]);
    bias_v[j] = (bias_v[j] == bias_v[j]) ? bias_v[j] : 0.f;
  }

  if (EPI == 0) {
    int which = n0 >> 11;             // 0:q 1:k 2:v  (uniform per block)
    int h = (n0 >> 7) & 15;           // uniform per block
    uint16_t* dst = which == 0 ? Cq : (which == 1 ? Ck : Cv);
#pragma unroll
    for (int i = 0; i < 4; i++)
#pragma unroll
      for (int j = 0; j < 4; j++) {
        int d = wn + j * 16 + l16;
#pragma unroll
        for (int r = 0; r < 4; r++) {
          int gm = m0 + wm + i * 16 + quad * 4 + r;
          int bi = gm >> 12, s = gm & 4095;
          float val = acc[i][j][r] + bias_v[j];
          size_t idx;
          if (which == 2) idx = ((size_t)(bi * HEADS + h) * 128 + d) * S_SZ + s;
          else            idx = ((size_t)(bi * HEADS + h) * S_SZ + s) * 128 + d;
          dst[idx] = f2bf(val);
        }
      }
  } else {
#pragma unroll
    for (int i = 0; i < 4; i++)
#pragma unroll
      for (int j = 0; j < 4; j++)
#pragma unroll
        for (int r = 0; r < 4; r++) {
          int gm = m0 + wm + i * 16 + quad * 4 + r;
          int gn = n0 + wn + j * 16 + l16;
          float val = acc[i][j][r] + bias_v[j];
          if (f32m) ((float*)Cout)[(size_t)gm * Ndim + gn] = val;
          else      Cout[(size_t)gm * Ndim + gn] = f2bf(val);
        }
  }
}

// ------------------------------------------------------------------- RoPE
__global__ __launch_bounds__(128) void rope_kernel(
    uint16_t* __restrict__ q, uint16_t* __restrict__ k,
    const uint16_t* __restrict__ position, const uint16_t* __restrict__ freqs,
    const uint32_t* __restrict__ flag) {
  const bool f32m = flag[0] != 0;
  int bs = blockIdx.x;                 // b*4096 + s
  int b = bs >> 12, s = bs & 4095;
  int tid = threadIdx.x;
  int f = tid & 63;
  uint16_t* base = (tid >> 6) ? k : q;
  float fr[3], ps[3];
#pragma unroll
  for (int c = 0; c < 3; c++) {
    fr[c] = f32m ? ((const float*)freqs)[f * 3 + c]    : bf2f(freqs[f * 3 + c]);
    ps[c] = f32m ? ((const float*)position)[s * 3 + c] : bf2f(position[s * 3 + c]);
  }
  float ang = fr[0] * ps[0] + fr[1] * ps[1] + fr[2] * ps[2];
  ang = (ang == ang) ? ang : 0.f;
  float sn = __sinf(ang), c = __cosf(ang);
#pragma unroll
  for (int h = 0; h < HEADS; h++) {
    size_t idx = ((size_t)(b * HEADS + h) * S_SZ + s) * 128 + 2 * f;
    uint32_t pair = *(const uint32_t*)&base[idx];
    float tr = bf2f((uint16_t)(pair & 0xFFFF));
    float ti = bf2f((uint16_t)(pair >> 16));
    float orr = tr * c - ti * sn;
    float oi  = tr * sn + ti * c;
    uint32_t op = (uint32_t)f2bf(orr) | ((uint32_t)f2bf(oi) << 16);
    *(uint32_t*)&base[idx] = op;
  }
}

// --------------------------------------------------------- flash attention
// grid: (S/64 q-tiles, B*H); block: 256 (4 waves x 16 q-rows)
// This round: K/V staging via global_load_lds width=16 (m97 pattern) —
// removes the global->reg->LDS round trip, its ds_writes, and all staging
// VGPRs. Swizzled layout preserved by PRE-SWIZZLING the per-lane global
// source address (XOR is an involution; LDS dest stays linear = HW order).
// Plain launch_bounds (r2's min-waves clamp caused an 8GB scratch spill).
__global__ __launch_bounds__(256) void flash_kernel(
    const uint16_t* __restrict__ q, const uint16_t* __restrict__ k,
    const uint16_t* __restrict__ vT, uint16_t* __restrict__ attn) {
  __shared__ __align__(16) uint16_t Ks[64 * 128];    // [t][d]  16KB, swizzled
  __shared__ __align__(16) uint16_t VTs[128 * 64];   // [d][t]  16KB, swizzled
  __shared__ __align__(16) uint16_t Ps[4][16 * 64];  // per-wave P  8KB, swizzled
  int tid = threadIdx.x, wave = tid >> 6, lane = tid & 63;
  int quad = lane >> 4, l16 = lane & 15;
  int bh = blockIdx.y;
  int b = bh >> 4, h = bh & 15;
  int q0 = blockIdx.x * 64;
  const uint16_t* qbase = q  + (size_t)bh * S_SZ * 128;
  const uint16_t* kbase = k  + (size_t)bh * S_SZ * 128;
  const uint16_t* vbase = vT + (size_t)bh * 128 * S_SZ;

  // Q fragments in registers (A-operand layout: row=l16, k=quad*8+j)
  bf16x8 aq[4];
  {
    const uint16_t* qrow = qbase + (size_t)(q0 + wave * 16 + l16) * 128;
#pragma unroll
    for (int kk = 0; kk < 4; kk++)
      aq[kk] = *(const bf16x8*)(qrow + kk * 32 + quad * 8);
  }
  float m_run[4], l_run[4];
#pragma unroll
  for (int r = 0; r < 4; r++) { m_run[r] = -1e30f; l_run[r] = 0.f; }
  f32x4 oacc[8] = {};
  const float scale = 0.08838834764831845f;   // 1/sqrt(128)

  // Per-lane pre-swizzled global byte offsets for the 4 K-chunks + 4 V-chunks
  // this wave stages (chunk = 1KB: 64 lanes x 16B). LDS slot for lane = linear
  // le = chunk_base + lane*8 elems; we fetch the element the swizzled READ
  // expects at that slot: src col = col ^ ((row&7)<<3).
  int koffb[4], voffb[4];
#pragma unroll
  for (int c = 0; c < 4; c++) {
    int le = (wave * 4 + c) * 512 + lane * 8;
    int krow = le >> 7, kcol = le & 127;
    koffb[c] = (krow * 128 + (kcol ^ ((krow & 7) << 3))) * 2;
    int vrow = le >> 6, vcol = le & 63;
    voffb[c] = (vrow * S_SZ + (vcol ^ ((vrow & 7) << 3))) * 2;
  }

  for (int t0 = 0; t0 < S_SZ; t0 += 64) {
    const uint8_t* kb = (const uint8_t*)kbase + (size_t)t0 * 256;  // t0*128 elem
    const uint8_t* vb = (const uint8_t*)vbase + (size_t)t0 * 2;    // t0 elem
#pragma unroll
    for (int c = 0; c < 4; c++) {
      gload_lds16(kb + koffb[c], &Ks[(wave * 4 + c) * 512]);
      gload_lds16(vb + voffb[c], &VTs[(wave * 4 + c) * 512]);
    }
    __syncthreads();   // compiler drains vmcnt before s_barrier -> LDS ready

    // S = Q K^T  (16 q-rows x 64 t per wave)
    f32x4 sacc[4] = {};
#pragma unroll
    for (int j = 0; j < 4; j++)
#pragma unroll
      for (int kk = 0; kk < 4; kk++) {
        bf16x8 bk = *(const bf16x8*)&Ks[swz128(j * 16 + l16, kk * 32 + quad * 8)];
        sacc[j] = __builtin_amdgcn_mfma_f32_16x16x32_bf16(aq[kk], bk, sacc[j], 0, 0, 0);
      }

    // online softmax (C rows = quad*4 + r)
    float p[4][4];
#pragma unroll
    for (int r = 0; r < 4; r++) {
      float mx = sacc[0][r];
#pragma unroll
      for (int j = 1; j < 4; j++) mx = fmaxf(mx, sacc[j][r]);
      mx *= scale;
#pragma unroll
      for (int off = 1; off < 16; off <<= 1) mx = fmaxf(mx, __shfl_xor(mx, off, 64));
      float mn = fmaxf(m_run[r], mx);
      float al = __expf(fminf(m_run[r] - mn, 0.f));
      float rs = 0.f;
#pragma unroll
      for (int j = 0; j < 4; j++) {
        float pv_ = __expf(fminf(sacc[j][r] * scale - mn, 0.f));
        p[j][r] = pv_; rs += pv_;
      }
#pragma unroll
      for (int off = 1; off < 16; off <<= 1) rs += __shfl_xor(rs, off, 64);
      l_run[r] = l_run[r] * al + rs;
      m_run[r] = mn;
#pragma unroll
      for (int jd = 0; jd < 8; jd++) oacc[jd][r] *= al;
    }

    // P: C-layout -> LDS -> A-layout. Ps is wave-private: no barrier needed,
    // the compiler's lgkmcnt wait orders the intra-wave ds_write->ds_read.
    uint16_t* ps = &Ps[wave][0];
#pragma unroll
    for (int j = 0; j < 4; j++)
#pragma unroll
      for (int r = 0; r < 4; r++)
        ps[swz64(quad * 4 + r, j * 16 + l16)] = f2bf(p[j][r]);

    bf16x8 ap[2];
#pragma unroll
    for (int kk = 0; kk < 2; kk++)
      ap[kk] = *(const bf16x8*)&ps[swz64(l16, kk * 32 + quad * 8)];
#pragma unroll
    for (int jd = 0; jd < 8; jd++)
#pragma unroll
      for (int kk = 0; kk < 2; kk++) {
        bf16x8 bv = *(const bf16x8*)&VTs[swz64(jd * 16 + l16, kk * 32 + quad * 8)];
        oacc[jd] = __builtin_amdgcn_mfma_f32_16x16x32_bf16(ap[kk], bv, oacc[jd], 0, 0, 0);
      }
    __syncthreads();
  }

  // normalize + write attn[b][s][h*128+d]  (l_run >= 1 by construction)
#pragma unroll
  for (int jd = 0; jd < 8; jd++)
#pragma unroll
    for (int r = 0; r < 4; r++) {
      int srow = q0 + wave * 16 + quad * 4 + r;
      int d = jd * 16 + l16;
      float ov = oacc[jd][r] / fmaxf(l_run[r], 1e-20f);
      attn[((size_t)(b * S_SZ + srow)) * E_SZ + h * 128 + d] = f2bf(ov);
    }
}

// ------------------------------------------------------------------ launch
extern "C" void kernel_launch(void* const* d_in, const int* in_sizes, int n_in,
                              void* d_out, int out_size, void* d_ws, size_t ws_size,
                              hipStream_t stream) {
  const uint16_t* x        = (const uint16_t*)d_in[0];
  const uint16_t* position = (const uint16_t*)d_in[1];
  const uint16_t* ln_w     = (const uint16_t*)d_in[2];
  const uint16_t* ln_b     = (const uint16_t*)d_in[3];
  const uint16_t* qkv_w    = (const uint16_t*)d_in[4];
  const uint16_t* qkv_b    = (const uint16_t*)d_in[5];
  const uint16_t* out_w    = (const uint16_t*)d_in[6];
  const uint16_t* out_b    = (const uint16_t*)d_in[7];
  const uint16_t* freqs    = (const uint16_t*)d_in[8];

  uint8_t* ws = (uint8_t*)d_ws;
  const size_t SLAB = (size_t)M_SZ * E_SZ * 2;   // 67,108,864 B
  uint32_t* flag = (uint32_t*)ws;
  uint16_t* xn   = (uint16_t*)(ws + 1024);       // reused as attn later
  uint16_t* kws  = (uint16_t*)(ws + 1024 + SLAB);
  uint16_t* vTws = (uint16_t*)(ws + 1024 + 2 * SLAB);
  uint16_t* qws  = (uint16_t*)d_out;             // q parks in d_out until final GEMM
  uint16_t* attn = xn;

  probe_kernel<<<1, 64, 0, stream>>>(x, flag);
  ln_kernel<<<M_SZ, 256, 0, stream>>>(x, ln_w, ln_b, xn, flag);
  gemm_bt<0><<<dim3(NQKV / 128, M_SZ / 128), 256, 0, stream>>>(
      xn, qkv_w, qkv_b, qws, kws, vTws, nullptr, 0, flag);
  rope_kernel<<<M_SZ, 128, 0, stream>>>(qws, kws, position, freqs, flag);
  flash_kernel<<<dim3(S_SZ / 64, B_SZ * HEADS), 256, 0, stream>>>(qws, kws, vTws, attn);
  gemm_bt<1><<<dim3(E_SZ / 128, M_SZ / 128), 256, 0, stream>>>(
      attn, out_w, out_b, nullptr, nullptr, nullptr, (uint16_t*)d_out, E_SZ, flag);
}

// Round 4
// 3001.784 us; speedup vs baseline: 1.9746x; 1.2868x over previous
//
#include <hip/hip_runtime.h>
#include <stdint.h>

#define HEADS 16
#define B_SZ  4
#define S_SZ  4096
#define E_SZ  2048
#define M_SZ  (B_SZ * S_SZ)      // 16384 rows
#define NQKV  (3 * E_SZ)         // 6144

typedef short bf16x8 __attribute__((ext_vector_type(8)));
typedef float f32x4  __attribute__((ext_vector_type(4)));

__device__ __forceinline__ float bf2f(uint16_t u) {
  union { uint32_t i; float f; } v; v.i = ((uint32_t)u) << 16; return v.f;
}
__device__ __forceinline__ uint16_t f2bf(float f) {
  union { float f; uint32_t i; } v; v.f = f;
  uint32_t r = v.i + 0x7FFFu + ((v.i >> 16) & 1u);   // RNE
  return (uint16_t)(r >> 16);
}

// XOR bank swizzles (flash LDS): column ^ ((row&7)<<3) — bijective within each
// 8-row stripe, preserves 16B alignment, spreads stride-256B/128B column reads
// across all 32 banks (residual 2-way = free). [verified r1: conflicts 7.3e8->6.7e7]
__device__ __forceinline__ int swz128(int row, int col) {  // col 0..127
  return row * 128 + (col ^ ((row & 7) << 3));
}
__device__ __forceinline__ int swz64(int row, int col) {   // col 0..63
  return row * 64 + (col ^ ((row & 7) << 3));
}

// direct global->LDS 16B copy; LDS dest is wave-uniform base + lane*16 (HW),
// global src is per-lane (pre-swizzled). Compiler never auto-emits this.
__device__ __forceinline__ void gload_lds16(const void* g, void* l) {
  __builtin_amdgcn_global_load_lds(
      (const __attribute__((address_space(1))) uint32_t*)g,
      (__attribute__((address_space(3))) uint32_t*)l, 16, 0, 0);
}

// ------------------------------------------------------------- dtype probe
// flag=1 -> inputs are f32 read as uint16 halves (garbage at even indices)
__global__ __launch_bounds__(64) void probe_kernel(
    const uint16_t* __restrict__ x, uint32_t* __restrict__ flag) {
  int tid = threadIdx.x;
  int cnt = 0;
  for (int i = tid; i < 4096; i += 64) {
    uint16_t u = x[2 * i];
    int e = (u >> 7) & 0xFF;
    cnt += (e >= 134) ? 1 : 0;    // |v| >= 128 or NaN/Inf: impossible for N(0,1) bf16
  }
#pragma unroll
  for (int off = 1; off < 64; off <<= 1) cnt += __shfl_xor(cnt, off, 64);
  if (tid == 0) flag[0] = (cnt > 256) ? 1u : 0u;
}

// ---------------------------------------------------------------- LayerNorm
__global__ __launch_bounds__(256) void ln_kernel(
    const uint16_t* __restrict__ x, const uint16_t* __restrict__ w,
    const uint16_t* __restrict__ b, uint16_t* __restrict__ xn,
    const uint32_t* __restrict__ flag) {
  const bool f32m = flag[0] != 0;
  int row = blockIdx.x;
  int tid = threadIdx.x;
  float v[8], wv[8], bv[8];
  if (f32m) {
    const float* xr = (const float*)x + (size_t)row * E_SZ;
    float4 a0 = ((const float4*)xr)[tid * 2], a1 = ((const float4*)xr)[tid * 2 + 1];
    v[0]=a0.x; v[1]=a0.y; v[2]=a0.z; v[3]=a0.w; v[4]=a1.x; v[5]=a1.y; v[6]=a1.z; v[7]=a1.w;
    const float* wf = (const float*)w; const float* bf = (const float*)b;
    float4 w0 = ((const float4*)wf)[tid * 2], w1 = ((const float4*)wf)[tid * 2 + 1];
    float4 b0 = ((const float4*)bf)[tid * 2], b1 = ((const float4*)bf)[tid * 2 + 1];
    wv[0]=w0.x; wv[1]=w0.y; wv[2]=w0.z; wv[3]=w0.w; wv[4]=w1.x; wv[5]=w1.y; wv[6]=w1.z; wv[7]=w1.w;
    bv[0]=b0.x; bv[1]=b0.y; bv[2]=b0.z; bv[3]=b0.w; bv[4]=b1.x; bv[5]=b1.y; bv[6]=b1.z; bv[7]=b1.w;
  } else {
    const uint16_t* xr = x + (size_t)row * E_SZ;
    uint4 pack = ((const uint4*)xr)[tid];
    uint4 wp = ((const uint4*)w)[tid];
    uint4 bp = ((const uint4*)b)[tid];
    const uint16_t* pu = (const uint16_t*)&pack;
    const uint16_t* pw = (const uint16_t*)&wp;
    const uint16_t* pb = (const uint16_t*)&bp;
#pragma unroll
    for (int i = 0; i < 8; i++) { v[i] = bf2f(pu[i]); wv[i] = bf2f(pw[i]); bv[i] = bf2f(pb[i]); }
  }
  float sum = 0.f, ss = 0.f;
#pragma unroll
  for (int i = 0; i < 8; i++) {
    v[i] = (v[i] == v[i]) ? v[i] : 0.f;        // scrub NaN (input-facing, keep)
    sum += v[i]; ss += v[i] * v[i];
  }
#pragma unroll
  for (int off = 1; off < 64; off <<= 1) {
    sum += __shfl_xor(sum, off, 64);
    ss  += __shfl_xor(ss,  off, 64);
  }
  __shared__ float s_sum[4], s_ss[4];
  int wave = tid >> 6, lane = tid & 63;
  if (lane == 0) { s_sum[wave] = sum; s_ss[wave] = ss; }
  __syncthreads();
  sum = s_sum[0] + s_sum[1] + s_sum[2] + s_sum[3];
  ss  = s_ss[0]  + s_ss[1]  + s_ss[2]  + s_ss[3];
  float mean = sum * (1.0f / E_SZ);
  float var  = fmaxf(ss * (1.0f / E_SZ) - mean * mean, 0.0f);
  float rstd = rsqrtf(var + 1e-5f);
  uint16_t o[8];
#pragma unroll
  for (int i = 0; i < 8; i++)
    o[i] = f2bf((v[i] - mean) * rstd * wv[i] + bv[i]);
  ((uint4*)(xn + (size_t)row * E_SZ))[tid] = *(const uint4*)o;
}

// ------------------------------------------------- 128x128 MFMA GEMM (B^T)
// C[m,n] = sum_k A[m,k]*Bm[n,k] + bias[n];  A is internal bf16 always.
// r1-proven structure (no reg-prefetch, no pad, plain launch_bounds); scrubs
// dropped (A/B are finite: internal bf16 / 0.02-scale weights; r2 verified).
// EPI==0: scatter qkv -> q[B,H,S,hd], k[B,H,S,hd], vT[B,H,hd,S] (internal bf16)
// EPI==1: row-major store to Cout[M][Ndim] (dtype per flag)
template <int EPI>
__global__ __launch_bounds__(256) void gemm_bt(
    const uint16_t* __restrict__ A, const uint16_t* __restrict__ Bm,
    const uint16_t* __restrict__ bias, uint16_t* __restrict__ Cq,
    uint16_t* __restrict__ Ck, uint16_t* __restrict__ Cv,
    uint16_t* __restrict__ Cout, int Ndim, const uint32_t* __restrict__ flag) {
  const bool f32m = flag[0] != 0;
  __shared__ __align__(16) uint16_t As[128 * 32];
  __shared__ __align__(16) uint16_t Bs[128 * 32];
  int tid = threadIdx.x;
  int wave = tid >> 6, lane = tid & 63;
  int quad = lane >> 4, l16 = lane & 15;
  int m0 = blockIdx.y * 128, n0 = blockIdx.x * 128;
  int wm = (wave >> 1) * 64, wn = (wave & 1) * 64;

  f32x4 acc[4][4] = {};

  for (int kt = 0; kt < E_SZ / 32; kt++) {
    int k0 = kt * 32;
#pragma unroll
    for (int r = 0; r < 2; r++) {
      int e = r * 2048 + tid * 8;       // element index in the 128x32 tile
      int rw = e >> 5, cl = e & 31;
      *(uint4*)&As[e] = *(const uint4*)(A + (size_t)(m0 + rw) * E_SZ + k0 + cl);
      if (f32m) {
        const float* Bf = (const float*)Bm + (size_t)(n0 + rw) * E_SZ + k0 + cl;
        float4 x0 = *(const float4*)(Bf);
        float4 x1 = *(const float4*)(Bf + 4);
        uint16_t pbv[8];
        pbv[0]=f2bf(x0.x); pbv[1]=f2bf(x0.y); pbv[2]=f2bf(x0.z); pbv[3]=f2bf(x0.w);
        pbv[4]=f2bf(x1.x); pbv[5]=f2bf(x1.y); pbv[6]=f2bf(x1.z); pbv[7]=f2bf(x1.w);
        *(uint4*)&Bs[e] = *(const uint4*)pbv;
      } else {
        *(uint4*)&Bs[e] = *(const uint4*)(Bm + (size_t)(n0 + rw) * E_SZ + k0 + cl);
      }
    }
    __syncthreads();
    bf16x8 a[4], bb[4];
#pragma unroll
    for (int i = 0; i < 4; i++)
      a[i] = *(const bf16x8*)&As[(wm + i * 16 + l16) * 32 + quad * 8];
#pragma unroll
    for (int j = 0; j < 4; j++)
      bb[j] = *(const bf16x8*)&Bs[(wn + j * 16 + l16) * 32 + quad * 8];
#pragma unroll
    for (int i = 0; i < 4; i++)
#pragma unroll
      for (int j = 0; j < 4; j++)
        acc[i][j] = __builtin_amdgcn_mfma_f32_16x16x32_bf16(a[i], bb[j], acc[i][j], 0, 0, 0);
    __syncthreads();
  }

  float bias_v[4];
#pragma unroll
  for (int j = 0; j < 4; j++) {
    int n = n0 + wn + j * 16 + l16;
    bias_v[j] = f32m ? ((const float*)bias)[n] : bf2f(bias[n]);
    bias_v[j] = (bias_v[j] == bias_v[j]) ? bias_v[j] : 0.f;
  }

  if (EPI == 0) {
    int which = n0 >> 11;             // 0:q 1:k 2:v  (uniform per block)
    int h = (n0 >> 7) & 15;           // uniform per block
    uint16_t* dst = which == 0 ? Cq : (which == 1 ? Ck : Cv);
#pragma unroll
    for (int i = 0; i < 4; i++)
#pragma unroll
      for (int j = 0; j < 4; j++) {
        int d = wn + j * 16 + l16;
#pragma unroll
        for (int r = 0; r < 4; r++) {
          int gm = m0 + wm + i * 16 + quad * 4 + r;
          int bi = gm >> 12, s = gm & 4095;
          float val = acc[i][j][r] + bias_v[j];
          size_t idx;
          if (which == 2) idx = ((size_t)(bi * HEADS + h) * 128 + d) * S_SZ + s;
          else            idx = ((size_t)(bi * HEADS + h) * S_SZ + s) * 128 + d;
          dst[idx] = f2bf(val);
        }
      }
  } else {
#pragma unroll
    for (int i = 0; i < 4; i++)
#pragma unroll
      for (int j = 0; j < 4; j++)
#pragma unroll
        for (int r = 0; r < 4; r++) {
          int gm = m0 + wm + i * 16 + quad * 4 + r;
          int gn = n0 + wn + j * 16 + l16;
          float val = acc[i][j][r] + bias_v[j];
          if (f32m) ((float*)Cout)[(size_t)gm * Ndim + gn] = val;
          else      Cout[(size_t)gm * Ndim + gn] = f2bf(val);
        }
  }
}

// ------------------------------------------------------------------- RoPE
__global__ __launch_bounds__(128) void rope_kernel(
    uint16_t* __restrict__ q, uint16_t* __restrict__ k,
    const uint16_t* __restrict__ position, const uint16_t* __restrict__ freqs,
    const uint32_t* __restrict__ flag) {
  const bool f32m = flag[0] != 0;
  int bs = blockIdx.x;                 // b*4096 + s
  int b = bs >> 12, s = bs & 4095;
  int tid = threadIdx.x;
  int f = tid & 63;
  uint16_t* base = (tid >> 6) ? k : q;
  float fr[3], ps[3];
#pragma unroll
  for (int c = 0; c < 3; c++) {
    fr[c] = f32m ? ((const float*)freqs)[f * 3 + c]    : bf2f(freqs[f * 3 + c]);
    ps[c] = f32m ? ((const float*)position)[s * 3 + c] : bf2f(position[s * 3 + c]);
  }
  float ang = fr[0] * ps[0] + fr[1] * ps[1] + fr[2] * ps[2];
  ang = (ang == ang) ? ang : 0.f;
  float sn = __sinf(ang), c = __cosf(ang);
#pragma unroll
  for (int h = 0; h < HEADS; h++) {
    size_t idx = ((size_t)(b * HEADS + h) * S_SZ + s) * 128 + 2 * f;
    uint32_t pair = *(const uint32_t*)&base[idx];
    float tr = bf2f((uint16_t)(pair & 0xFFFF));
    float ti = bf2f((uint16_t)(pair >> 16));
    float orr = tr * c - ti * sn;
    float oi  = tr * sn + ti * c;
    uint32_t op = (uint32_t)f2bf(orr) | ((uint32_t)f2bf(oi) << 16);
    *(uint32_t*)&base[idx] = op;
  }
}

// --------------------------------------------------------- flash attention
// grid: (S/64 q-tiles, B*H); block: 256 (4 waves x 16 q-rows)
// This round: T3-minimal 2-phase pipeline. Ks/VTs double-buffered; the NEXT
// tile's global_load_lds are issued right after the top-of-loop barrier and
// stay in flight under the current tile's full compute phase (~1600 cyc >>
// HBM latency). The next barrier's vmcnt(0) drain then completes instantly.
// One barrier per tile (was two). r3 exposed the load latency serially every
// tile (MfmaUtil 9.7%, no pipe >30%). LDS 72KB -> 2 blocks/CU.
__global__ __launch_bounds__(256) void flash_kernel(
    const uint16_t* __restrict__ q, const uint16_t* __restrict__ k,
    const uint16_t* __restrict__ vT, uint16_t* __restrict__ attn) {
  __shared__ __align__(16) uint16_t Ks[2][64 * 128];   // [t][d]  2x16KB, swizzled
  __shared__ __align__(16) uint16_t VTs[2][128 * 64];  // [d][t]  2x16KB, swizzled
  __shared__ __align__(16) uint16_t Ps[4][16 * 64];    // per-wave P  8KB, swizzled
  int tid = threadIdx.x, wave = tid >> 6, lane = tid & 63;
  int quad = lane >> 4, l16 = lane & 15;
  int bh = blockIdx.y;
  int b = bh >> 4, h = bh & 15;
  int q0 = blockIdx.x * 64;
  const uint16_t* qbase = q  + (size_t)bh * S_SZ * 128;
  const uint16_t* kbase = k  + (size_t)bh * S_SZ * 128;
  const uint16_t* vbase = vT + (size_t)bh * 128 * S_SZ;

  // Q fragments in registers (A-operand layout: row=l16, k=quad*8+j)
  bf16x8 aq[4];
  {
    const uint16_t* qrow = qbase + (size_t)(q0 + wave * 16 + l16) * 128;
#pragma unroll
    for (int kk = 0; kk < 4; kk++)
      aq[kk] = *(const bf16x8*)(qrow + kk * 32 + quad * 8);
  }
  float m_run[4], l_run[4];
#pragma unroll
  for (int r = 0; r < 4; r++) { m_run[r] = -1e30f; l_run[r] = 0.f; }
  f32x4 oacc[8] = {};
  const float scale = 0.08838834764831845f;   // 1/sqrt(128)

  // Per-lane pre-swizzled global byte offsets for the 4 K-chunks + 4 V-chunks
  // this wave stages (chunk = 1KB: 64 lanes x 16B). LDS slot for lane = linear
  // le = chunk_base + lane*8 elems; we fetch the element the swizzled READ
  // expects at that slot: src col = col ^ ((row&7)<<3).
  int koffb[4], voffb[4];
#pragma unroll
  for (int c = 0; c < 4; c++) {
    int le = (wave * 4 + c) * 512 + lane * 8;
    int krow = le >> 7, kcol = le & 127;
    koffb[c] = (krow * 128 + (kcol ^ ((krow & 7) << 3))) * 2;
    int vrow = le >> 6, vcol = le & 63;
    voffb[c] = (vrow * S_SZ + (vcol ^ ((vrow & 7) << 3))) * 2;
  }

  auto STAGE = [&](int t0, int buf) {
    const uint8_t* kb = (const uint8_t*)kbase + (size_t)t0 * 256;  // t0*128 elem
    const uint8_t* vb = (const uint8_t*)vbase + (size_t)t0 * 2;    // t0 elem
#pragma unroll
    for (int c = 0; c < 4; c++) {
      gload_lds16(kb + koffb[c], &Ks[buf][(wave * 4 + c) * 512]);
      gload_lds16(vb + voffb[c], &VTs[buf][(wave * 4 + c) * 512]);
    }
  };

  STAGE(0, 0);
  int cur = 0;
  for (int t0 = 0; t0 < S_SZ; t0 += 64) {
    // drains vmcnt: completes the stage of buf[cur] (in flight for a full
    // compute phase) and guarantees everyone finished reading buf[cur^1].
    __syncthreads();
    if (t0 + 64 < S_SZ) STAGE(t0 + 64, cur ^ 1);   // next tile, other buffer

    const uint16_t* ks = Ks[cur];
    const uint16_t* vs = VTs[cur];

    // S = Q K^T  (16 q-rows x 64 t per wave)
    f32x4 sacc[4] = {};
#pragma unroll
    for (int j = 0; j < 4; j++)
#pragma unroll
      for (int kk = 0; kk < 4; kk++) {
        bf16x8 bk = *(const bf16x8*)&ks[swz128(j * 16 + l16, kk * 32 + quad * 8)];
        sacc[j] = __builtin_amdgcn_mfma_f32_16x16x32_bf16(aq[kk], bk, sacc[j], 0, 0, 0);
      }

    // online softmax (C rows = quad*4 + r)
    float p[4][4];
#pragma unroll
    for (int r = 0; r < 4; r++) {
      float mx = sacc[0][r];
#pragma unroll
      for (int j = 1; j < 4; j++) mx = fmaxf(mx, sacc[j][r]);
      mx *= scale;
#pragma unroll
      for (int off = 1; off < 16; off <<= 1) mx = fmaxf(mx, __shfl_xor(mx, off, 64));
      float mn = fmaxf(m_run[r], mx);
      float al = __expf(fminf(m_run[r] - mn, 0.f));
      float rs = 0.f;
#pragma unroll
      for (int j = 0; j < 4; j++) {
        float pv_ = __expf(fminf(sacc[j][r] * scale - mn, 0.f));
        p[j][r] = pv_; rs += pv_;
      }
#pragma unroll
      for (int off = 1; off < 16; off <<= 1) rs += __shfl_xor(rs, off, 64);
      l_run[r] = l_run[r] * al + rs;
      m_run[r] = mn;
#pragma unroll
      for (int jd = 0; jd < 8; jd++) oacc[jd][r] *= al;
    }

    // P: C-layout -> LDS -> A-layout. Ps is wave-private: no barrier needed,
    // the compiler's lgkmcnt wait orders the intra-wave ds_write->ds_read.
    uint16_t* ps = &Ps[wave][0];
#pragma unroll
    for (int j = 0; j < 4; j++)
#pragma unroll
      for (int r = 0; r < 4; r++)
        ps[swz64(quad * 4 + r, j * 16 + l16)] = f2bf(p[j][r]);

    bf16x8 ap[2];
#pragma unroll
    for (int kk = 0; kk < 2; kk++)
      ap[kk] = *(const bf16x8*)&ps[swz64(l16, kk * 32 + quad * 8)];
#pragma unroll
    for (int jd = 0; jd < 8; jd++)
#pragma unroll
      for (int kk = 0; kk < 2; kk++) {
        bf16x8 bv = *(const bf16x8*)&vs[swz64(jd * 16 + l16, kk * 32 + quad * 8)];
        oacc[jd] = __builtin_amdgcn_mfma_f32_16x16x32_bf16(ap[kk], bv, oacc[jd], 0, 0, 0);
      }
    cur ^= 1;
  }

  // normalize + write attn[b][s][h*128+d]  (l_run >= 1 by construction)
#pragma unroll
  for (int jd = 0; jd < 8; jd++)
#pragma unroll
    for (int r = 0; r < 4; r++) {
      int srow = q0 + wave * 16 + quad * 4 + r;
      int d = jd * 16 + l16;
      float ov = oacc[jd][r] / fmaxf(l_run[r], 1e-20f);
      attn[((size_t)(b * S_SZ + srow)) * E_SZ + h * 128 + d] = f2bf(ov);
    }
}

// ------------------------------------------------------------------ launch
extern "C" void kernel_launch(void* const* d_in, const int* in_sizes, int n_in,
                              void* d_out, int out_size, void* d_ws, size_t ws_size,
                              hipStream_t stream) {
  const uint16_t* x        = (const uint16_t*)d_in[0];
  const uint16_t* position = (const uint16_t*)d_in[1];
  const uint16_t* ln_w     = (const uint16_t*)d_in[2];
  const uint16_t* ln_b     = (const uint16_t*)d_in[3];
  const uint16_t* qkv_w    = (const uint16_t*)d_in[4];
  const uint16_t* qkv_b    = (const uint16_t*)d_in[5];
  const uint16_t* out_w    = (const uint16_t*)d_in[6];
  const uint16_t* out_b    = (const uint16_t*)d_in[7];
  const uint16_t* freqs    = (const uint16_t*)d_in[8];

  uint8_t* ws = (uint8_t*)d_ws;
  const size_t SLAB = (size_t)M_SZ * E_SZ * 2;   // 67,108,864 B
  uint32_t* flag = (uint32_t*)ws;
  uint16_t* xn   = (uint16_t*)(ws + 1024);       // reused as attn later
  uint16_t* kws  = (uint16_t*)(ws + 1024 + SLAB);
  uint16_t* vTws = (uint16_t*)(ws + 1024 + 2 * SLAB);
  uint16_t* qws  = (uint16_t*)d_out;             // q parks in d_out until final GEMM
  uint16_t* attn = xn;

  probe_kernel<<<1, 64, 0, stream>>>(x, flag);
  ln_kernel<<<M_SZ, 256, 0, stream>>>(x, ln_w, ln_b, xn, flag);
  gemm_bt<0><<<dim3(NQKV / 128, M_SZ / 128), 256, 0, stream>>>(
      xn, qkv_w, qkv_b, qws, kws, vTws, nullptr, 0, flag);
  rope_kernel<<<M_SZ, 128, 0, stream>>>(qws, kws, position, freqs, flag);
  flash_kernel<<<dim3(S_SZ / 64, B_SZ * HEADS), 256, 0, stream>>>(qws, kws, vTws, attn);
  gemm_bt<1><<<dim3(E_SZ / 128, M_SZ / 128), 256, 0, stream>>>(
      attn, out_w, out_b, nullptr, nullptr, nullptr, (uint16_t*)d_out, E_SZ, flag);
}